// Round 7
// baseline (4923.434 us; speedup 1.0000x reference)
//
#include <hip/hip_runtime.h>
#include <cstdint>
#include <cstddef>

#define BD 32
#define TD 4096
#define ID 256
#define OD 256

// f32 constants, computed in f64 and rounded (matches np.exp on f32 within <=1 ulp)
#define A_DEND 0.90483741803595957f   // exp(-1/10)
#define A_SYN  0.81873075307798182f   // exp(-1/5)
#define A_MEM  0.95122942450071402f   // exp(-1/20)
#define TWO_PI_F 6.28318530717958647692f
#define BASE_DTH 62.8318530717958647692f  // 2*pi*10
#define INV256 0.00390625f

#define DOT4(acc, xv, wv)               \
  acc = fmaf((xv).x, (wv).x, acc);      \
  acc = fmaf((xv).y, (wv).y, acc);      \
  acc = fmaf((xv).z, (wv).z, acc);      \
  acc = fmaf((xv).w, (wv).w, acc);

// direct global->LDS DMA, width 16 B (dest = wave-uniform base + lane*16)
__device__ __forceinline__ void gload_lds16(const float* g, float* l) {
  __builtin_amdgcn_global_load_lds(
      (const __attribute__((address_space(1))) unsigned int*)g,
      (__attribute__((address_space(3))) unsigned int*)l,
      16, 0, 0);
}

// ---------------------------------------------------------------------------
// Phase A v5 = v4 + anti-spill sched_barrier.
// v4 post-mortem: VGPR=128 + WRITE_SIZE 7.5 GB = scratch spill. Static
// pressure ~107 (acc 56 + xv 32 + wv 4 + addr) fits 128, but the scheduler's
// cross-q ds_read hoisting added ~30 regs -> spilled acc in the hot loop.
// Fix: __builtin_amdgcn_sched_barrier(0) per q-iteration pins the region;
// within a q all 15 ds_reads may still batch ahead of the 224 fmacs (covers
// LDS latency), across q no hoisting -> pressure ~= static count.
// Structure (unchanged, passed bit-identical): block = 512 thr, 16 o-cols x
// 256 m-rows; weights 112x260 in LDS once (116 KB, 2-way reads = free);
// x double-buffered 16-k chunks (32 KB) via global_load_lds width=16.
// Balance per wave per q: 15 b128 (~150 cyc/CU) : 224 fmac (448 cyc/SIMD)
// -> VALU-bound once spill-free (floor 765 us).
// ---------------------------------------------------------------------------

#define WSTR 260   // weight row stride (floats); 1040 B, 16-B aligned, 2-way banks

__global__ __launch_bounds__(512, 1)
void proj_kernel(const float* __restrict__ x,
                 const float* __restrict__ Ws,
                 const float* __restrict__ Wb,
                 const float* __restrict__ Wa,
                 float* __restrict__ soma_ws,
                 float* __restrict__ u_ws) {
  #pragma clang fp contract(off)
  __shared__ float wl[112 * WSTR];   // 116,480 B
  __shared__ float xsf[2 * 4096];    //  32,768 B  (2 bufs x 256 rows x 16 k)

  const int tid = threadIdx.x;
  const int l   = tid & 63;
  const int w   = tid >> 6;          // wave id 0..7

  // bijective XCD-aware mapping: 16 o-blocks of one m-slab -> same XCD
  const int bid    = (int)blockIdx.x;          // 0..8191
  const int slot   = bid >> 3;                 // 0..1023
  const int family = ((slot >> 4) << 3) + (bid & 7);   // m-slab 0..511
  const int within = slot & 15;                // o-group 0..15
  const int o0     = within << 4;
  const int slab0  = family << 8;              // first m-row (x256)

  // ---- stage weights via global_load_lds: rep r = rep*8+w is wave-uniform,
  //      dest wl + r*260 + lane*4 floats == uniform base + lane*16 B ----
  #pragma unroll
  for (int rep = 0; rep < 14; ++rep) {
    const int r = (rep << 3) + w;    // 0..111, uniform per wave
    const float* src;
    if (r < 16) {
      src = Ws + (((size_t)(o0 + r)) << 8);
    } else if (r < 80) {
      src = Wb + (((size_t)((((r - 16) >> 4) << 8) + o0 + (r & 15))) << 8);
    } else {
      src = Wa + (((size_t)((((r - 80) >> 4) << 8) + o0 + (r & 15))) << 8);
    }
    gload_lds16(src + (l << 2), wl + r * WSTR);
  }

  // x chunk staging geometry: chunk = 256 rows x 16 k = 1024 float4;
  // thread covers f = tid and tid+512; row = f>>2, kq = f&3.
  const float4* g0 = (const float4*)x + ((size_t)(slab0 + (tid >> 2)) << 6) + (tid & 3);
  const float4* g1 = g0 + (128 << 6);          // rows +128
  const int wb4 = ((tid >> 6) << 6) << 2;      // wave base, floats (w*64 float4)
  // stage chunk 0 -> buf 0
  gload_lds16((const float*)g0, xsf + wb4);
  gload_lds16((const float*)g1, xsf + wb4 + 2048);

  const int oo = tid & 15;
  const int mg = tid >> 4;                     // 0..31
  const float* wA = wl + oo * WSTR;            // p = 0..3 via +p*4160 floats
  const float* wB = wA + 4 * 16 * WSTR;        // p = 4..6
  const float* xbf = xsf + (mg << 4);          // + r*512 + q*4 (+4096 for buf1)

  float acc[7][8];
  #pragma unroll
  for (int p = 0; p < 7; ++p) {
    #pragma unroll
    for (int r = 0; r < 8; ++r) acc[p][r] = 0.f;
  }

  __syncthreads();   // drains all staging DMAs (vmcnt) + joins waves

#define K4GROUP(XOFF, WOFF)                                                \
  _Pragma("unroll")                                                        \
  for (int q = 0; q < 4; ++q) {                                            \
    float4 xv[8];                                                          \
    _Pragma("unroll")                                                      \
    for (int r = 0; r < 8; ++r)                                            \
      xv[r] = *(const float4*)(xbf + (XOFF) + r * 512 + (q << 2));         \
    _Pragma("unroll")                                                      \
    for (int p = 0; p < 7; ++p) {                                          \
      const float* wp = (p < 4) ? (wA + p * 16 * WSTR)                     \
                                : (wB + (p - 4) * 16 * WSTR);              \
      float4 wv = *(const float4*)(wp + (WOFF) + (q << 2));                \
      DOT4(acc[p][0], xv[0], wv) DOT4(acc[p][1], xv[1], wv)                \
      DOT4(acc[p][2], xv[2], wv) DOT4(acc[p][3], xv[3], wv)                \
      DOT4(acc[p][4], xv[4], wv) DOT4(acc[p][5], xv[5], wv)                \
      DOT4(acc[p][6], xv[6], wv) DOT4(acc[p][7], xv[7], wv)                \
    }                                                                      \
    __builtin_amdgcn_sched_barrier(0);  /* no cross-q hoist: cap pressure */ \
  }

  for (int c = 0; c < 8; ++c) {
    // chunk 2c: compute buf0, prefetch chunk 2c+1 -> buf1
    gload_lds16((const float*)(g0 + 4), xsf + 4096 + wb4);
    gload_lds16((const float*)(g1 + 4), xsf + 4096 + wb4 + 2048);
    K4GROUP(0, 0)
    __syncthreads();
    // chunk 2c+1: compute buf1, prefetch chunk 2c+2 -> buf0
    if (c < 7) {
      gload_lds16((const float*)(g0 + 8), xsf + wb4);
      gload_lds16((const float*)(g1 + 8), xsf + wb4 + 2048);
    }
    K4GROUP(4096, 16)
    __syncthreads();
    wA += 32; wB += 32; g0 += 8; g1 += 8;   // advance k by 32 floats / 8 float4
  }

  // epilogue: identical expressions/roundings to the round-1 passing kernel
  #pragma unroll
  for (int r = 0; r < 8; ++r) {
    const size_t off = (((size_t)slab0 + mg + (r << 5)) << 8) + o0 + oo;
    float bm = ((fmaxf(acc[1][r], 0.f) + fmaxf(acc[2][r], 0.f)) +
                (fmaxf(acc[3][r], 0.f) + fmaxf(acc[4][r], 0.f))) * 0.25f;
    float am = (fmaxf(acc[5][r], 0.f) + fmaxf(acc[6][r], 0.f)) * 0.5f;
    soma_ws[off] = acc[0][r];
    u_ws[off]    = bm + am;
  }
}

// ---------------------------------------------------------------------------
// Phase B: sequential LIF + Kuramoto. Round-1-verified geometry (32 blocks x
// 1 wave, ~1.3-1.4 ms) kept UNCHANGED: multi-wave variants regressed 2x in
// rounds 2-3 and dyn has never yet appeared in the top-5 counters. With proj
// at ~1.1 ms, dyn becomes the top dispatch next round and gets profiled.
// Lane owns o=4l..4l+3; DPP wave64 sums; depth-2 (A/B) prefetch;
// spike=(v>0) is bit-identical to sg+(hh-sg) in f32.
// ---------------------------------------------------------------------------

#define DPP_ADD(v, ctrl, rm, bm, bc)                                          \
  v += __builtin_bit_cast(float, __builtin_amdgcn_update_dpp(                 \
           0, __builtin_bit_cast(int, v), ctrl, rm, bm, bc));

__device__ __forceinline__ float wave_sum64(float v) {
  DPP_ADD(v, 0x111, 0xf, 0xf, true)    // row_shr:1
  DPP_ADD(v, 0x112, 0xf, 0xf, true)    // row_shr:2
  DPP_ADD(v, 0x114, 0xf, 0xf, true)    // row_shr:4
  DPP_ADD(v, 0x118, 0xf, 0xf, true)    // row_shr:8
  DPP_ADD(v, 0x142, 0xa, 0xf, false)   // row_bcast:15 -> rows 1,3
  DPP_ADD(v, 0x143, 0xc, 0xf, false)   // row_bcast:31 -> rows 2,3
  return __builtin_bit_cast(float, __builtin_amdgcn_readlane(__builtin_bit_cast(int, v), 63));
}

#define PROCESS4(TBASE)                                                       \
  _Pragma("unroll")                                                           \
  for (int i = 0; i < 4; ++i) {                                               \
    const int t = (TBASE) + i;                                                \
    const float* sv = &cs[i].x;                                               \
    const float* uv = &cu[i].x;                                               \
    float spk[4], cc[4], ss[4];                                               \
    _Pragma("unroll")                                                         \
    for (int j = 0; j < 4; ++j) {                                             \
      float t1 = A_DEND * dend[j];                                            \
      float t2 = bD * uv[j];                                                  \
      dend[j] = t1 + t2;                                                      \
      float drive = sv[j] + 0.5f * dend[j];                                   \
      syn[j] = (A_SYN * syn[j]) + drive;                                      \
      mem[j] = (A_MEM * mem[j]) + syn[j];                                     \
      float v = mem[j] - 1.0f;                                                \
      float sp = (v > 0.0f) ? 1.0f : 0.0f;                                    \
      mem[j] = mem[j] - sp;                                                   \
      spk[j] = sp;                                                            \
      cc[j] = __cosf(th[j]);                                                  \
      ss[j] = __sinf(th[j]);                                                  \
    }                                                                         \
    float csum = (cc[0] + cc[1]) + (cc[2] + cc[3]);                           \
    float ssum = (ss[0] + ss[1]) + (ss[2] + ss[3]);                           \
    float cS = wave_sum64(csum);                                              \
    float sS = wave_sum64(ssum);                                              \
    _Pragma("unroll")                                                         \
    for (int j = 0; j < 4; ++j) {                                             \
      float coup = (sS * cc[j] - cS * ss[j]) * INV256;                        \
      float dth = (BASE_DTH + coup) + spk[j];                                 \
      th[j] = th[j] + 0.001f * dth;                                           \
      th[j] = (th[j] >= TWO_PI_F) ? (th[j] - TWO_PI_F) : th[j];               \
    }                                                                         \
    float4 so = {spk[0], spk[1], spk[2], spk[3]};                             \
    float4 po = {th[0], th[1], th[2], th[3]};                                 \
    float4 mo = {mem[0], mem[1], mem[2], mem[3]};                             \
    Os[(size_t)t * 64] = so;                                                  \
    Op[(size_t)t * 64] = po;                                                  \
    Om[(size_t)t * 64] = mo;                                                  \
  }

__global__ __launch_bounds__(64, 1)
void dyn_kernel(const float* __restrict__ soma_ws,
                const float* __restrict__ u_ws,
                float* __restrict__ out) {
  // Match numpy's per-op rounding: no mul+add fusion except explicit fmaf.
  #pragma clang fp contract(off)
  const int b = blockIdx.x;
  const int l = threadIdx.x;

  const size_t base4 = ((size_t)b << 18) + l;        // float4 units
  const float4* S = (const float4*)soma_ws + base4;
  const float4* U = (const float4*)u_ws + base4;
  float4* Os = (float4*)out + base4;                 // spikes
  float4* Op = Os + ((size_t)1 << 23);               // phases
  float4* Om = Op + ((size_t)1 << 23);               // membrane

  float dend[4] = {0.f, 0.f, 0.f, 0.f};
  float syn[4]  = {0.f, 0.f, 0.f, 0.f};
  float mem[4]  = {0.f, 0.f, 0.f, 0.f};
  float th[4]   = {0.f, 0.f, 0.f, 0.f};

  const float bD = 1.0f - A_DEND;   // exact (Sterbenz)

  float4 As[4], Au[4], Bs[4], Bu[4];
  #pragma unroll
  for (int i = 0; i < 4; ++i) { As[i] = S[(size_t)i * 64];       Au[i] = U[(size_t)i * 64]; }
  #pragma unroll
  for (int i = 0; i < 4; ++i) { Bs[i] = S[(size_t)(4 + i) * 64]; Bu[i] = U[(size_t)(4 + i) * 64]; }

  for (int t8 = 0; t8 < TD / 8; ++t8) {
    float4 cs[4], cu[4];
    #pragma unroll
    for (int i = 0; i < 4; ++i) { cs[i] = As[i]; cu[i] = Au[i]; }
    if (t8 < TD / 8 - 1) {         // refill A with chunk 2*t8+2
      #pragma unroll
      for (int i = 0; i < 4; ++i) {
        As[i] = S[(size_t)((t8 << 3) + 8 + i) * 64];
        Au[i] = U[(size_t)((t8 << 3) + 8 + i) * 64];
      }
    }
    PROCESS4((t8 << 3));
    #pragma unroll
    for (int i = 0; i < 4; ++i) { cs[i] = Bs[i]; cu[i] = Bu[i]; }
    if (t8 < TD / 8 - 1) {         // refill B with chunk 2*t8+3
      #pragma unroll
      for (int i = 0; i < 4; ++i) {
        Bs[i] = S[(size_t)((t8 << 3) + 12 + i) * 64];
        Bu[i] = U[(size_t)((t8 << 3) + 12 + i) * 64];
      }
    }
    PROCESS4((t8 << 3) + 4);
  }
}

// ---------------------------------------------------------------------------

extern "C" void kernel_launch(void* const* d_in, const int* in_sizes, int n_in,
                              void* d_out, int out_size, void* d_ws, size_t ws_size,
                              hipStream_t stream) {
  const float* x  = (const float*)d_in[0];
  const float* Ws = (const float*)d_in[1];
  const float* Wb = (const float*)d_in[2];
  const float* Wa = (const float*)d_in[3];

  float* soma_ws = (float*)d_ws;
  float* u_ws    = soma_ws + (size_t)BD * TD * OD;   // +33554432 floats
  float* out     = (float*)d_out;

  proj_kernel<<<8192, 512, 0, stream>>>(x, Ws, Wb, Wa, soma_ws, u_ws);
  dyn_kernel<<<BD, 64, 0, stream>>>(soma_ws, u_ws, out);
}

// Round 8
// 4884.780 us; speedup vs baseline: 1.0079x; 1.0079x over previous
//
#include <hip/hip_runtime.h>
#include <cstdint>
#include <cstddef>

#define BD 32
#define TD 4096
#define ID 256
#define OD 256

// f32 constants, computed in f64 and rounded (matches np.exp on f32 within <=1 ulp)
#define A_DEND 0.90483741803595957f   // exp(-1/10)
#define A_SYN  0.81873075307798182f   // exp(-1/5)
#define A_MEM  0.95122942450071402f   // exp(-1/20)
#define TWO_PI_F 6.28318530717958647692f
#define BASE_DTH 62.8318530717958647692f  // 2*pi*10
#define INV256 0.00390625f

#define DOT4(acc, xv, wv)               \
  acc = fmaf((xv).x, (wv).x, acc);      \
  acc = fmaf((xv).y, (wv).y, acc);      \
  acc = fmaf((xv).z, (wv).z, acc);      \
  acc = fmaf((xv).w, (wv).w, acc);

// direct global->LDS DMA, width 16 B (dest = wave-uniform base + lane*16)
__device__ __forceinline__ void gload_lds16(const float* g, float* l) {
  __builtin_amdgcn_global_load_lds(
      (const __attribute__((address_space(1))) unsigned int*)g,
      (__attribute__((address_space(3))) unsigned int*)l,
      16, 0, 0);
}

// ---------------------------------------------------------------------------
// Phase A v6 = v5 with ONE change: __launch_bounds__(512, 2).
// v5/v7 post-mortem: VGPR=128 + WRITE_SIZE 8 GB (spill stores -> L2 dirty ->
// HBM writeback; reloads hit L2, hence FETCH stays low). Cause theory: for a
// 512-thread block, launch_bounds arg2=1 means k=0.5 blocks/CU (nonsense) ->
// compiler ignores it and applies its default 4-waves/EU heuristic -> 128
// VGPR cap -> spill. arg2=2 legally encodes 1 block/CU -> 256 VGPR cap.
// Evidence: round-3 proj used (512,2) and allocated 112 spill-free; every
// spilled round used (512,1). Occupancy can't drop: LDS=149KB already
// limits to 1 block/CU.
// Structure (unchanged, passes bit-identical): block = 512 thr, 16 o-cols x
// 256 m-rows; weights 112x260 in LDS once (116 KB, 2-way reads = free);
// x double-buffered 16-k chunks (32 KB) via global_load_lds width=16.
// ---------------------------------------------------------------------------

#define WSTR 260   // weight row stride (floats); 1040 B, 16-B aligned, 2-way banks

__global__ __launch_bounds__(512, 2)
void proj_kernel(const float* __restrict__ x,
                 const float* __restrict__ Ws,
                 const float* __restrict__ Wb,
                 const float* __restrict__ Wa,
                 float* __restrict__ soma_ws,
                 float* __restrict__ u_ws) {
  #pragma clang fp contract(off)
  __shared__ float wl[112 * WSTR];   // 116,480 B
  __shared__ float xsf[2 * 4096];    //  32,768 B  (2 bufs x 256 rows x 16 k)

  const int tid = threadIdx.x;
  const int l   = tid & 63;
  const int w   = tid >> 6;          // wave id 0..7

  // bijective XCD-aware mapping: 16 o-blocks of one m-slab -> same XCD
  const int bid    = (int)blockIdx.x;          // 0..8191
  const int slot   = bid >> 3;                 // 0..1023
  const int family = ((slot >> 4) << 3) + (bid & 7);   // m-slab 0..511
  const int within = slot & 15;                // o-group 0..15
  const int o0     = within << 4;
  const int slab0  = family << 8;              // first m-row (x256)

  // ---- stage weights via global_load_lds: rep r = rep*8+w is wave-uniform,
  //      dest wl + r*260 + lane*4 floats == uniform base + lane*16 B ----
  #pragma unroll
  for (int rep = 0; rep < 14; ++rep) {
    const int r = (rep << 3) + w;    // 0..111, uniform per wave
    const float* src;
    if (r < 16) {
      src = Ws + (((size_t)(o0 + r)) << 8);
    } else if (r < 80) {
      src = Wb + (((size_t)((((r - 16) >> 4) << 8) + o0 + (r & 15))) << 8);
    } else {
      src = Wa + (((size_t)((((r - 80) >> 4) << 8) + o0 + (r & 15))) << 8);
    }
    gload_lds16(src + (l << 2), wl + r * WSTR);
  }

  // x chunk staging geometry: chunk = 256 rows x 16 k = 1024 float4;
  // thread covers f = tid and tid+512; row = f>>2, kq = f&3.
  const float4* g0 = (const float4*)x + ((size_t)(slab0 + (tid >> 2)) << 6) + (tid & 3);
  const float4* g1 = g0 + (128 << 6);          // rows +128
  const int wb4 = ((tid >> 6) << 6) << 2;      // wave base, floats (w*64 float4)
  // stage chunk 0 -> buf 0
  gload_lds16((const float*)g0, xsf + wb4);
  gload_lds16((const float*)g1, xsf + wb4 + 2048);

  const int oo = tid & 15;
  const int mg = tid >> 4;                     // 0..31
  const float* wA = wl + oo * WSTR;            // p = 0..3 via +p*4160 floats
  const float* wB = wA + 4 * 16 * WSTR;        // p = 4..6
  const float* xbf = xsf + (mg << 4);          // + r*512 + q*4 (+4096 for buf1)

  float acc[7][8];
  #pragma unroll
  for (int p = 0; p < 7; ++p) {
    #pragma unroll
    for (int r = 0; r < 8; ++r) acc[p][r] = 0.f;
  }

  __syncthreads();   // drains all staging DMAs (vmcnt) + joins waves

#define K4GROUP(XOFF, WOFF)                                                \
  _Pragma("unroll")                                                        \
  for (int q = 0; q < 4; ++q) {                                            \
    float4 xv[8];                                                          \
    _Pragma("unroll")                                                      \
    for (int r = 0; r < 8; ++r)                                            \
      xv[r] = *(const float4*)(xbf + (XOFF) + r * 512 + (q << 2));         \
    _Pragma("unroll")                                                      \
    for (int p = 0; p < 7; ++p) {                                          \
      const float* wp = (p < 4) ? (wA + p * 16 * WSTR)                     \
                                : (wB + (p - 4) * 16 * WSTR);              \
      float4 wv = *(const float4*)(wp + (WOFF) + (q << 2));                \
      DOT4(acc[p][0], xv[0], wv) DOT4(acc[p][1], xv[1], wv)                \
      DOT4(acc[p][2], xv[2], wv) DOT4(acc[p][3], xv[3], wv)                \
      DOT4(acc[p][4], xv[4], wv) DOT4(acc[p][5], xv[5], wv)                \
      DOT4(acc[p][6], xv[6], wv) DOT4(acc[p][7], xv[7], wv)                \
    }                                                                      \
    __builtin_amdgcn_sched_barrier(0);  /* no cross-q hoist: cap pressure */ \
  }

  for (int c = 0; c < 8; ++c) {
    // chunk 2c: compute buf0, prefetch chunk 2c+1 -> buf1
    gload_lds16((const float*)(g0 + 4), xsf + 4096 + wb4);
    gload_lds16((const float*)(g1 + 4), xsf + 4096 + wb4 + 2048);
    K4GROUP(0, 0)
    __syncthreads();
    // chunk 2c+1: compute buf1, prefetch chunk 2c+2 -> buf0
    if (c < 7) {
      gload_lds16((const float*)(g0 + 8), xsf + wb4);
      gload_lds16((const float*)(g1 + 8), xsf + wb4 + 2048);
    }
    K4GROUP(4096, 16)
    __syncthreads();
    wA += 32; wB += 32; g0 += 8; g1 += 8;   // advance k by 32 floats / 8 float4
  }

  // epilogue: identical expressions/roundings to the round-1 passing kernel
  #pragma unroll
  for (int r = 0; r < 8; ++r) {
    const size_t off = (((size_t)slab0 + mg + (r << 5)) << 8) + o0 + oo;
    float bm = ((fmaxf(acc[1][r], 0.f) + fmaxf(acc[2][r], 0.f)) +
                (fmaxf(acc[3][r], 0.f) + fmaxf(acc[4][r], 0.f))) * 0.25f;
    float am = (fmaxf(acc[5][r], 0.f) + fmaxf(acc[6][r], 0.f)) * 0.5f;
    soma_ws[off] = acc[0][r];
    u_ws[off]    = bm + am;
  }
}

// ---------------------------------------------------------------------------
// Phase B: sequential LIF + Kuramoto. Round-1-verified geometry (32 blocks x
// 1 wave) kept UNCHANGED: multi-wave variants regressed 2x in rounds 2-3 and
// dyn has never yet appeared in the top-5 counters. With proj at ~1.2 ms,
// dyn becomes a top dispatch next round and gets profiled before touching.
// Lane owns o=4l..4l+3; DPP wave64 sums; depth-2 (A/B) prefetch;
// spike=(v>0) is bit-identical to sg+(hh-sg) in f32.
// ---------------------------------------------------------------------------

#define DPP_ADD(v, ctrl, rm, bm, bc)                                          \
  v += __builtin_bit_cast(float, __builtin_amdgcn_update_dpp(                 \
           0, __builtin_bit_cast(int, v), ctrl, rm, bm, bc));

__device__ __forceinline__ float wave_sum64(float v) {
  DPP_ADD(v, 0x111, 0xf, 0xf, true)    // row_shr:1
  DPP_ADD(v, 0x112, 0xf, 0xf, true)    // row_shr:2
  DPP_ADD(v, 0x114, 0xf, 0xf, true)    // row_shr:4
  DPP_ADD(v, 0x118, 0xf, 0xf, true)    // row_shr:8
  DPP_ADD(v, 0x142, 0xa, 0xf, false)   // row_bcast:15 -> rows 1,3
  DPP_ADD(v, 0x143, 0xc, 0xf, false)   // row_bcast:31 -> rows 2,3
  return __builtin_bit_cast(float, __builtin_amdgcn_readlane(__builtin_bit_cast(int, v), 63));
}

#define PROCESS4(TBASE)                                                       \
  _Pragma("unroll")                                                           \
  for (int i = 0; i < 4; ++i) {                                               \
    const int t = (TBASE) + i;                                                \
    const float* sv = &cs[i].x;                                               \
    const float* uv = &cu[i].x;                                               \
    float spk[4], cc[4], ss[4];                                               \
    _Pragma("unroll")                                                         \
    for (int j = 0; j < 4; ++j) {                                             \
      float t1 = A_DEND * dend[j];                                            \
      float t2 = bD * uv[j];                                                  \
      dend[j] = t1 + t2;                                                      \
      float drive = sv[j] + 0.5f * dend[j];                                   \
      syn[j] = (A_SYN * syn[j]) + drive;                                      \
      mem[j] = (A_MEM * mem[j]) + syn[j];                                     \
      float v = mem[j] - 1.0f;                                                \
      float sp = (v > 0.0f) ? 1.0f : 0.0f;                                    \
      mem[j] = mem[j] - sp;                                                   \
      spk[j] = sp;                                                            \
      cc[j] = __cosf(th[j]);                                                  \
      ss[j] = __sinf(th[j]);                                                  \
    }                                                                         \
    float csum = (cc[0] + cc[1]) + (cc[2] + cc[3]);                           \
    float ssum = (ss[0] + ss[1]) + (ss[2] + ss[3]);                           \
    float cS = wave_sum64(csum);                                              \
    float sS = wave_sum64(ssum);                                              \
    _Pragma("unroll")                                                         \
    for (int j = 0; j < 4; ++j) {                                             \
      float coup = (sS * cc[j] - cS * ss[j]) * INV256;                        \
      float dth = (BASE_DTH + coup) + spk[j];                                 \
      th[j] = th[j] + 0.001f * dth;                                           \
      th[j] = (th[j] >= TWO_PI_F) ? (th[j] - TWO_PI_F) : th[j];               \
    }                                                                         \
    float4 so = {spk[0], spk[1], spk[2], spk[3]};                             \
    float4 po = {th[0], th[1], th[2], th[3]};                                 \
    float4 mo = {mem[0], mem[1], mem[2], mem[3]};                             \
    Os[(size_t)t * 64] = so;                                                  \
    Op[(size_t)t * 64] = po;                                                  \
    Om[(size_t)t * 64] = mo;                                                  \
  }

__global__ __launch_bounds__(64, 1)
void dyn_kernel(const float* __restrict__ soma_ws,
                const float* __restrict__ u_ws,
                float* __restrict__ out) {
  // Match numpy's per-op rounding: no mul+add fusion except explicit fmaf.
  #pragma clang fp contract(off)
  const int b = blockIdx.x;
  const int l = threadIdx.x;

  const size_t base4 = ((size_t)b << 18) + l;        // float4 units
  const float4* S = (const float4*)soma_ws + base4;
  const float4* U = (const float4*)u_ws + base4;
  float4* Os = (float4*)out + base4;                 // spikes
  float4* Op = Os + ((size_t)1 << 23);               // phases
  float4* Om = Op + ((size_t)1 << 23);               // membrane

  float dend[4] = {0.f, 0.f, 0.f, 0.f};
  float syn[4]  = {0.f, 0.f, 0.f, 0.f};
  float mem[4]  = {0.f, 0.f, 0.f, 0.f};
  float th[4]   = {0.f, 0.f, 0.f, 0.f};

  const float bD = 1.0f - A_DEND;   // exact (Sterbenz)

  float4 As[4], Au[4], Bs[4], Bu[4];
  #pragma unroll
  for (int i = 0; i < 4; ++i) { As[i] = S[(size_t)i * 64];       Au[i] = U[(size_t)i * 64]; }
  #pragma unroll
  for (int i = 0; i < 4; ++i) { Bs[i] = S[(size_t)(4 + i) * 64]; Bu[i] = U[(size_t)(4 + i) * 64]; }

  for (int t8 = 0; t8 < TD / 8; ++t8) {
    float4 cs[4], cu[4];
    #pragma unroll
    for (int i = 0; i < 4; ++i) { cs[i] = As[i]; cu[i] = Au[i]; }
    if (t8 < TD / 8 - 1) {         // refill A with chunk 2*t8+2
      #pragma unroll
      for (int i = 0; i < 4; ++i) {
        As[i] = S[(size_t)((t8 << 3) + 8 + i) * 64];
        Au[i] = U[(size_t)((t8 << 3) + 8 + i) * 64];
      }
    }
    PROCESS4((t8 << 3));
    #pragma unroll
    for (int i = 0; i < 4; ++i) { cs[i] = Bs[i]; cu[i] = Bu[i]; }
    if (t8 < TD / 8 - 1) {         // refill B with chunk 2*t8+3
      #pragma unroll
      for (int i = 0; i < 4; ++i) {
        Bs[i] = S[(size_t)((t8 << 3) + 12 + i) * 64];
        Bu[i] = U[(size_t)((t8 << 3) + 12 + i) * 64];
      }
    }
    PROCESS4((t8 << 3) + 4);
  }
}

// ---------------------------------------------------------------------------

extern "C" void kernel_launch(void* const* d_in, const int* in_sizes, int n_in,
                              void* d_out, int out_size, void* d_ws, size_t ws_size,
                              hipStream_t stream) {
  const float* x  = (const float*)d_in[0];
  const float* Ws = (const float*)d_in[1];
  const float* Wb = (const float*)d_in[2];
  const float* Wa = (const float*)d_in[3];

  float* soma_ws = (float*)d_ws;
  float* u_ws    = soma_ws + (size_t)BD * TD * OD;   // +33554432 floats
  float* out     = (float*)d_out;

  proj_kernel<<<8192, 512, 0, stream>>>(x, Ws, Wb, Wa, soma_ws, u_ws);
  dyn_kernel<<<BD, 64, 0, stream>>>(soma_ws, u_ws, out);
}

// Round 9
// 4829.252 us; speedup vs baseline: 1.0195x; 1.0115x over previous
//
#include <hip/hip_runtime.h>
#include <cstdint>
#include <cstddef>

#define BD 32
#define TD 4096
#define ID 256
#define OD 256

// f32 constants, computed in f64 and rounded (matches np.exp on f32 within <=1 ulp)
#define A_DEND 0.90483741803595957f   // exp(-1/10)
#define A_SYN  0.81873075307798182f   // exp(-1/5)
#define A_MEM  0.95122942450071402f   // exp(-1/20)
#define TWO_PI_F 6.28318530717958647692f
#define BASE_DTH 62.8318530717958647692f  // 2*pi*10
#define INV256 0.00390625f

#define DOT4(acc, xv, wv)               \
  acc = fmaf((xv).x, (wv).x, acc);      \
  acc = fmaf((xv).y, (wv).y, acc);      \
  acc = fmaf((xv).z, (wv).z, acc);      \
  acc = fmaf((xv).w, (wv).w, acc);

// direct global->LDS DMA, width 16 B (dest = wave-uniform base + lane*16)
__device__ __forceinline__ void gload_lds16(const float* g, float* l) {
  __builtin_amdgcn_global_load_lds(
      (const __attribute__((address_space(1))) unsigned int*)g,
      (__attribute__((address_space(3))) unsigned int*)l,
      16, 0, 0);
}

// ---------------------------------------------------------------------------
// Phase A v7: spill fix from both sides.
// Allocation history: r3 static~95 -> 112 alloc OK; r5/r7/r8 static~110 ->
// 128 + 8 GB spill-writeback, regardless of launch_bounds arg2. Conclusion:
// the VGPR budget is 128 under every launch_bounds we tried (hipcc treats
// arg2 CUDA-style / defaults to 4 waves-EU), so:
//  (1) state occupancy with the unambiguous clang attributes:
//      amdgpu_flat_work_group_size(512,512) + amdgpu_waves_per_eu(2,2)
//      (truthful: 149 KB LDS -> 1 block/CU = 2 waves/EU) -> budget 256;
//  (2) drop static pressure to ~96 by construction: preload wv[7] per q
//      (28 live) and make xv transient (4), replacing xv[8]-live (32).
//      This is exactly the shape that allocated cleanly in round 3.
// LDS instr balance unchanged: 15 b128 per q per wave : 224 fmac.
// Per-output fmaf chain (k-ascending DOT4) unchanged -> bit-identical.
// ---------------------------------------------------------------------------

#define WSTR 260   // weight row stride (floats); 1040 B, 16-B aligned, 2-way banks

__global__ __attribute__((amdgpu_flat_work_group_size(512, 512),
                          amdgpu_waves_per_eu(2, 2)))
void proj_kernel(const float* __restrict__ x,
                 const float* __restrict__ Ws,
                 const float* __restrict__ Wb,
                 const float* __restrict__ Wa,
                 float* __restrict__ soma_ws,
                 float* __restrict__ u_ws) {
  #pragma clang fp contract(off)
  __shared__ float wl[112 * WSTR];   // 116,480 B
  __shared__ float xsf[2 * 4096];    //  32,768 B  (2 bufs x 256 rows x 16 k)

  const int tid = threadIdx.x;
  const int l   = tid & 63;
  const int w   = tid >> 6;          // wave id 0..7

  // bijective XCD-aware mapping: 16 o-blocks of one m-slab -> same XCD
  const int bid    = (int)blockIdx.x;          // 0..8191
  const int slot   = bid >> 3;                 // 0..1023
  const int family = ((slot >> 4) << 3) + (bid & 7);   // m-slab 0..511
  const int within = slot & 15;                // o-group 0..15
  const int o0     = within << 4;
  const int slab0  = family << 8;              // first m-row (x256)

  // ---- stage weights via global_load_lds: rep r = rep*8+w is wave-uniform,
  //      dest wl + r*260 + lane*4 floats == uniform base + lane*16 B ----
  #pragma unroll
  for (int rep = 0; rep < 14; ++rep) {
    const int r = (rep << 3) + w;    // 0..111, uniform per wave
    const float* src;
    if (r < 16) {
      src = Ws + (((size_t)(o0 + r)) << 8);
    } else if (r < 80) {
      src = Wb + (((size_t)((((r - 16) >> 4) << 8) + o0 + (r & 15))) << 8);
    } else {
      src = Wa + (((size_t)((((r - 80) >> 4) << 8) + o0 + (r & 15))) << 8);
    }
    gload_lds16(src + (l << 2), wl + r * WSTR);
  }

  // x chunk staging geometry: chunk = 256 rows x 16 k = 1024 float4;
  // thread covers f = tid and tid+512; row = f>>2, kq = f&3.
  const float4* g0 = (const float4*)x + ((size_t)(slab0 + (tid >> 2)) << 6) + (tid & 3);
  const float4* g1 = g0 + (128 << 6);          // rows +128
  const int wb4 = ((tid >> 6) << 6) << 2;      // wave base, floats (w*64 float4)
  // stage chunk 0 -> buf 0
  gload_lds16((const float*)g0, xsf + wb4);
  gload_lds16((const float*)g1, xsf + wb4 + 2048);

  const int oo = tid & 15;
  const int mg = tid >> 4;                     // 0..31
  const float* wA = wl + oo * WSTR;            // p = 0..3 via +p*4160 floats
  const float* wB = wA + 4 * 16 * WSTR;        // p = 4..6
  const float* xbf = xsf + (mg << 4);          // + r*512 + q*4 (+4096 for buf1)

  float acc[7][8];
  #pragma unroll
  for (int p = 0; p < 7; ++p) {
    #pragma unroll
    for (int r = 0; r < 8; ++r) acc[p][r] = 0.f;
  }

  __syncthreads();   // drains all staging DMAs (vmcnt) + joins waves

// wv[7] live per q (28 regs), xv transient (4): static pressure ~96.
#define K4GROUP(XOFF, WOFF)                                                \
  _Pragma("unroll")                                                        \
  for (int q = 0; q < 4; ++q) {                                            \
    float4 wv[7];                                                          \
    wv[0] = *(const float4*)(wA + 0 * 16 * WSTR + (WOFF) + (q << 2));      \
    wv[1] = *(const float4*)(wA + 1 * 16 * WSTR + (WOFF) + (q << 2));      \
    wv[2] = *(const float4*)(wA + 2 * 16 * WSTR + (WOFF) + (q << 2));      \
    wv[3] = *(const float4*)(wA + 3 * 16 * WSTR + (WOFF) + (q << 2));      \
    wv[4] = *(const float4*)(wB + 0 * 16 * WSTR + (WOFF) + (q << 2));      \
    wv[5] = *(const float4*)(wB + 1 * 16 * WSTR + (WOFF) + (q << 2));      \
    wv[6] = *(const float4*)(wB + 2 * 16 * WSTR + (WOFF) + (q << 2));      \
    _Pragma("unroll")                                                      \
    for (int r = 0; r < 8; ++r) {                                          \
      float4 xv = *(const float4*)(xbf + (XOFF) + r * 512 + (q << 2));     \
      DOT4(acc[0][r], xv, wv[0])                                           \
      DOT4(acc[1][r], xv, wv[1])                                           \
      DOT4(acc[2][r], xv, wv[2])                                           \
      DOT4(acc[3][r], xv, wv[3])                                           \
      DOT4(acc[4][r], xv, wv[4])                                           \
      DOT4(acc[5][r], xv, wv[5])                                           \
      DOT4(acc[6][r], xv, wv[6])                                           \
    }                                                                      \
    __builtin_amdgcn_sched_barrier(0);  /* no cross-q hoist: cap pressure */ \
  }

  for (int c = 0; c < 8; ++c) {
    // chunk 2c: compute buf0, prefetch chunk 2c+1 -> buf1
    gload_lds16((const float*)(g0 + 4), xsf + 4096 + wb4);
    gload_lds16((const float*)(g1 + 4), xsf + 4096 + wb4 + 2048);
    K4GROUP(0, 0)
    __syncthreads();
    // chunk 2c+1: compute buf1, prefetch chunk 2c+2 -> buf0
    if (c < 7) {
      gload_lds16((const float*)(g0 + 8), xsf + wb4);
      gload_lds16((const float*)(g1 + 8), xsf + wb4 + 2048);
    }
    K4GROUP(4096, 16)
    __syncthreads();
    wA += 32; wB += 32; g0 += 8; g1 += 8;   // advance k by 32 floats / 8 float4
  }

  // epilogue: identical expressions/roundings to the round-1 passing kernel
  #pragma unroll
  for (int r = 0; r < 8; ++r) {
    const size_t off = (((size_t)slab0 + mg + (r << 5)) << 8) + o0 + oo;
    float bm = ((fmaxf(acc[1][r], 0.f) + fmaxf(acc[2][r], 0.f)) +
                (fmaxf(acc[3][r], 0.f) + fmaxf(acc[4][r], 0.f))) * 0.25f;
    float am = (fmaxf(acc[5][r], 0.f) + fmaxf(acc[6][r], 0.f)) * 0.5f;
    soma_ws[off] = acc[0][r];
    u_ws[off]    = bm + am;
  }
}

// ---------------------------------------------------------------------------
// Phase B: sequential LIF + Kuramoto. Round-1-verified geometry (32 blocks x
// 1 wave) kept UNCHANGED: multi-wave variants regressed 2x in rounds 2-3 and
// dyn has never yet appeared in the top-5 counters. With proj at ~1.2 ms,
// dyn becomes a top dispatch next round and gets profiled before touching.
// Lane owns o=4l..4l+3; DPP wave64 sums; depth-2 (A/B) prefetch;
// spike=(v>0) is bit-identical to sg+(hh-sg) in f32.
// ---------------------------------------------------------------------------

#define DPP_ADD(v, ctrl, rm, bm, bc)                                          \
  v += __builtin_bit_cast(float, __builtin_amdgcn_update_dpp(                 \
           0, __builtin_bit_cast(int, v), ctrl, rm, bm, bc));

__device__ __forceinline__ float wave_sum64(float v) {
  DPP_ADD(v, 0x111, 0xf, 0xf, true)    // row_shr:1
  DPP_ADD(v, 0x112, 0xf, 0xf, true)    // row_shr:2
  DPP_ADD(v, 0x114, 0xf, 0xf, true)    // row_shr:4
  DPP_ADD(v, 0x118, 0xf, 0xf, true)    // row_shr:8
  DPP_ADD(v, 0x142, 0xa, 0xf, false)   // row_bcast:15 -> rows 1,3
  DPP_ADD(v, 0x143, 0xc, 0xf, false)   // row_bcast:31 -> rows 2,3
  return __builtin_bit_cast(float, __builtin_amdgcn_readlane(__builtin_bit_cast(int, v), 63));
}

#define PROCESS4(TBASE)                                                       \
  _Pragma("unroll")                                                           \
  for (int i = 0; i < 4; ++i) {                                               \
    const int t = (TBASE) + i;                                                \
    const float* sv = &cs[i].x;                                               \
    const float* uv = &cu[i].x;                                               \
    float spk[4], cc[4], ss[4];                                               \
    _Pragma("unroll")                                                         \
    for (int j = 0; j < 4; ++j) {                                             \
      float t1 = A_DEND * dend[j];                                            \
      float t2 = bD * uv[j];                                                  \
      dend[j] = t1 + t2;                                                      \
      float drive = sv[j] + 0.5f * dend[j];                                   \
      syn[j] = (A_SYN * syn[j]) + drive;                                      \
      mem[j] = (A_MEM * mem[j]) + syn[j];                                     \
      float v = mem[j] - 1.0f;                                                \
      float sp = (v > 0.0f) ? 1.0f : 0.0f;                                    \
      mem[j] = mem[j] - sp;                                                   \
      spk[j] = sp;                                                            \
      cc[j] = __cosf(th[j]);                                                  \
      ss[j] = __sinf(th[j]);                                                  \
    }                                                                         \
    float csum = (cc[0] + cc[1]) + (cc[2] + cc[3]);                           \
    float ssum = (ss[0] + ss[1]) + (ss[2] + ss[3]);                           \
    float cS = wave_sum64(csum);                                              \
    float sS = wave_sum64(ssum);                                              \
    _Pragma("unroll")                                                         \
    for (int j = 0; j < 4; ++j) {                                             \
      float coup = (sS * cc[j] - cS * ss[j]) * INV256;                        \
      float dth = (BASE_DTH + coup) + spk[j];                                 \
      th[j] = th[j] + 0.001f * dth;                                           \
      th[j] = (th[j] >= TWO_PI_F) ? (th[j] - TWO_PI_F) : th[j];               \
    }                                                                         \
    float4 so = {spk[0], spk[1], spk[2], spk[3]};                             \
    float4 po = {th[0], th[1], th[2], th[3]};                                 \
    float4 mo = {mem[0], mem[1], mem[2], mem[3]};                             \
    Os[(size_t)t * 64] = so;                                                  \
    Op[(size_t)t * 64] = po;                                                  \
    Om[(size_t)t * 64] = mo;                                                  \
  }

__global__ __launch_bounds__(64, 1)
void dyn_kernel(const float* __restrict__ soma_ws,
                const float* __restrict__ u_ws,
                float* __restrict__ out) {
  // Match numpy's per-op rounding: no mul+add fusion except explicit fmaf.
  #pragma clang fp contract(off)
  const int b = blockIdx.x;
  const int l = threadIdx.x;

  const size_t base4 = ((size_t)b << 18) + l;        // float4 units
  const float4* S = (const float4*)soma_ws + base4;
  const float4* U = (const float4*)u_ws + base4;
  float4* Os = (float4*)out + base4;                 // spikes
  float4* Op = Os + ((size_t)1 << 23);               // phases
  float4* Om = Op + ((size_t)1 << 23);               // membrane

  float dend[4] = {0.f, 0.f, 0.f, 0.f};
  float syn[4]  = {0.f, 0.f, 0.f, 0.f};
  float mem[4]  = {0.f, 0.f, 0.f, 0.f};
  float th[4]   = {0.f, 0.f, 0.f, 0.f};

  const float bD = 1.0f - A_DEND;   // exact (Sterbenz)

  float4 As[4], Au[4], Bs[4], Bu[4];
  #pragma unroll
  for (int i = 0; i < 4; ++i) { As[i] = S[(size_t)i * 64];       Au[i] = U[(size_t)i * 64]; }
  #pragma unroll
  for (int i = 0; i < 4; ++i) { Bs[i] = S[(size_t)(4 + i) * 64]; Bu[i] = U[(size_t)(4 + i) * 64]; }

  for (int t8 = 0; t8 < TD / 8; ++t8) {
    float4 cs[4], cu[4];
    #pragma unroll
    for (int i = 0; i < 4; ++i) { cs[i] = As[i]; cu[i] = Au[i]; }
    if (t8 < TD / 8 - 1) {         // refill A with chunk 2*t8+2
      #pragma unroll
      for (int i = 0; i < 4; ++i) {
        As[i] = S[(size_t)((t8 << 3) + 8 + i) * 64];
        Au[i] = U[(size_t)((t8 << 3) + 8 + i) * 64];
      }
    }
    PROCESS4((t8 << 3));
    #pragma unroll
    for (int i = 0; i < 4; ++i) { cs[i] = Bs[i]; cu[i] = Bu[i]; }
    if (t8 < TD / 8 - 1) {         // refill B with chunk 2*t8+3
      #pragma unroll
      for (int i = 0; i < 4; ++i) {
        Bs[i] = S[(size_t)((t8 << 3) + 12 + i) * 64];
        Bu[i] = U[(size_t)((t8 << 3) + 12 + i) * 64];
      }
    }
    PROCESS4((t8 << 3) + 4);
  }
}

// ---------------------------------------------------------------------------

extern "C" void kernel_launch(void* const* d_in, const int* in_sizes, int n_in,
                              void* d_out, int out_size, void* d_ws, size_t ws_size,
                              hipStream_t stream) {
  const float* x  = (const float*)d_in[0];
  const float* Ws = (const float*)d_in[1];
  const float* Wb = (const float*)d_in[2];
  const float* Wa = (const float*)d_in[3];

  float* soma_ws = (float*)d_ws;
  float* u_ws    = soma_ws + (size_t)BD * TD * OD;   // +33554432 floats
  float* out     = (float*)d_out;

  proj_kernel<<<8192, 512, 0, stream>>>(x, Ws, Wb, Wa, soma_ws, u_ws);
  dyn_kernel<<<BD, 64, 0, stream>>>(soma_ws, u_ws, out);
}